// Round 11
// baseline (117.214 us; speedup 1.0000x reference)
//
#include <hip/hip_runtime.h>

// out = X A + 1 r^T,  A = scale Wq^T (K^T V).  With G = X^T X, s = X^T 1:
//   K^T V = Wk G Wv^T + (Wk s) bv^T + bk (Wv s)^T + S bk bv^T
// Augment Wq+ = [Wq^T; bq^T; 0pad] (896x768) so r = col 768 of At.
//   prep_w: Wqt+/Wkt/Wvb (bf16) + zero csum
//   prep_x: Xbf [4][4096][768], Xt [4][768][4096], csum atomics
//   gram2:  2496 tri 64x64 split-K Gram partial tiles (K=512, split=8)
//           + u/d2/c2p aux
//   redvec2: reduce Gp (8 splits, 78 64x64 tiles) -> G (mirror); c1p;
//            168 64x64 P+ tiles spread over all 4 y-slices
//   C1+ = P+ ⊠ G            [4][896][768]   (gemm64: 672 wgs)
//   At  = Wvb ⊠ C1+ (+rank2)[4][768][896]   (gemm64: 672 wgs)
//   out = Xbf ⊠ At (K=768) + At[col][768] epilogue  fp32
//         (gemm_r64x128: 1536 wgs, 6 blocks/CU)
// GEMM: serial LDS loop (m97 structure), global_load_lds(16B) pre-swizzled
// source, XOR (r&7)<<4 reads, XCD-chunked bijective blockIdx swizzle.
// Tile-size model (R4..R10): serial-core dispatches are latency-bound until
// ~8 blocks/CU, then staging-BW-bound. Tile choice per dispatch:
//   - 64x64 where occupancy <3 blocks/CU and operands L2-fit (gram2, C1, At)
//   - 64x128 rect for gemm3: A=Xbf is HBM-resident (re-reads costly, keep
//     at 128-level) while B=At is L2-resident (re-reads cheap) -> occupancy
//     3->6 blocks/CU with A traffic unchanged (R9's 64x64 doubled A: +3us)
// (R1: dbuf+counted-vmcnt regressed; R2: P+ move regressed; R3: fused
//  reduce 6x regression; R4/R5: split 4/16 regressed -> split=8 optimal.
//  R7: FAILED on gram2 grid arithmetic — aux budget must cover all rows.)

typedef __attribute__((ext_vector_type(8))) __bf16 bf16x8;
typedef __attribute__((ext_vector_type(4))) float f32x4;

#define SCALE 0.03608439182435161f

union FragU {
    uint4 q;
    bf16x8 f;
    unsigned short s[8];
};

__device__ __forceinline__ unsigned short f2bf(float x) {
    unsigned int u = __builtin_bit_cast(unsigned int, x);
    u = (u + 0x7fffu + ((u >> 16) & 1u)) >> 16;
    return (unsigned short)u;
}
__device__ __forceinline__ float bf2f(unsigned short u) {
    unsigned int v = ((unsigned int)u) << 16;
    return __builtin_bit_cast(float, v);
}

__device__ __forceinline__ unsigned xcd_swizzle(unsigned lin, unsigned nwg) {
    const unsigned q = nwg >> 3, rr8 = nwg & 7;
    const unsigned xcd = lin & 7, o = lin >> 3;
    return (xcd < rr8 ? xcd * (q + 1) : rr8 * (q + 1) + (xcd - rr8) * q) + o;
}

// 16KB staging for 128-row panel: wave w covers rows [w*32, w*32+32).
__device__ __forceinline__ void stage_gl(const unsigned short* __restrict__ srcRowBase,
                                         int ldElems, char* lds, int wave, int lane) {
#pragma unroll
    for (int p = 0; p < 4; ++p) {
        int slotbase = (wave * 4 + p) * 1024;
        int slot = slotbase + lane * 16;
        int r = slot >> 7;
        int cb = (slot & 127) ^ ((r & 7) << 4);
        const char* g = (const char*)(srcRowBase + (size_t)r * ldElems) + cb;
        __builtin_amdgcn_global_load_lds(
            (const __attribute__((address_space(1))) unsigned int*)g,
            (__attribute__((address_space(3))) unsigned int*)(lds + slotbase),
            16, 0, 0);
    }
}

// 8KB half-size staging: half in {0,1} covers rows [half*32, half*32+32).
__device__ __forceinline__ void stage_gl64(const unsigned short* __restrict__ srcRowBase,
                                           int ldElems, char* lds, int half, int lane) {
#pragma unroll
    for (int p = 0; p < 4; ++p) {
        int slotbase = (half * 4 + p) * 1024;
        int slot = slotbase + lane * 16;
        int r = slot >> 7;
        int cb = (slot & 127) ^ ((r & 7) << 4);
        const char* g = (const char*)(srcRowBase + (size_t)r * ldElems) + cb;
        __builtin_amdgcn_global_load_lds(
            (const __attribute__((address_space(1))) unsigned int*)g,
            (__attribute__((address_space(3))) unsigned int*)(lds + slotbase),
            16, 0, 0);
    }
}

__device__ __forceinline__ bf16x8 load_frag(const char* lds, int row, int kbyte) {
    int a = row * 128 + kbyte;
    a ^= (row & 7) << 4;
    FragU u;
    u.q = *(const uint4*)(lds + a);
    return u.f;
}

// 64x64 serial core: 4 waves as 2x2 of 32x32; waves 0-1 stage A, 2-3 stage B.
__device__ __forceinline__ void gemm_core64(const unsigned short* __restrict__ Ab,
                                            const unsigned short* __restrict__ Bb,
                                            int K, int lda, int ldb,
                                            char* ldsA, char* ldsB,
                                            int wave, int lane, int wr, int wc,
                                            int l15, int khi, f32x4 (&acc)[2][2]) {
    for (int k0 = 0; k0 < K; k0 += 64) {
        if (wave < 2)
            stage_gl64(Ab + k0, lda, ldsA, wave, lane);
        else
            stage_gl64(Bb + k0, ldb, ldsB, wave - 2, lane);
        __syncthreads();
#pragma unroll
        for (int kk = 0; kk < 2; ++kk) {
            const int kbyte = kk * 64 + khi;
            bf16x8 af[2], bfr[2];
#pragma unroll
            for (int i = 0; i < 2; ++i)
                af[i] = load_frag(ldsA, wr * 32 + i * 16 + l15, kbyte);
#pragma unroll
            for (int j = 0; j < 2; ++j)
                bfr[j] = load_frag(ldsB, wc * 32 + j * 16 + l15, kbyte);
#pragma unroll
            for (int i = 0; i < 2; ++i)
#pragma unroll
                for (int j = 0; j < 2; ++j)
                    acc[i][j] = __builtin_amdgcn_mfma_f32_16x16x32_bf16(
                        af[i], bfr[j], acc[i][j], 0, 0, 0);
        }
        __syncthreads();
    }
}

enum { BIAS_NONE = 0, BIAS_RANK2 = 2, BIAS_RCOL = 3 };

// 64x128-tile GEMM (M=64, N=128): 4 waves side-by-side in N, each 64x32.
// A (64 rows, 8KB) staged by waves 0-1; B (128 rows, 16KB) by all 4 waves.
// For dispatches where A re-reads are HBM-costly but B is L2-resident.
template <int BIASM, bool OUT_BF16>
__global__ __launch_bounds__(256, 2) void gemm_r64x128(
    const unsigned short* __restrict__ A, const unsigned short* __restrict__ B,
    void* __restrict__ C,
    const float* __restrict__ p0, const float* __restrict__ p1,
    const float* __restrict__ p2, const float* __restrict__ p3,
    const unsigned short* __restrict__ rsrc,
    int K, int lda, int ldb, int ldc, long bsA, long bsB, long bsC,
    float scale, int vld1) {
    __shared__ __align__(16) char ldsA[8192];
    __shared__ __align__(16) char ldsB[16384];

    const unsigned gx = gridDim.x, gy = gridDim.y;
    const unsigned lin = blockIdx.x + gx * (blockIdx.y + gy * blockIdx.z);
    const unsigned wg = xcd_swizzle(lin, gx * gy * gridDim.z);
    const int bx = wg % gx;
    const int by = (wg / gx) % gy;
    const int z = wg / (gx * gy);

    const int m0 = by * 64;
    const int n0 = bx * 128;
    const unsigned short* Ab = A + (size_t)z * bsA + (size_t)m0 * lda;
    const unsigned short* Bb = B + (size_t)z * bsB + (size_t)n0 * ldb;

    const int lane = threadIdx.x & 63;
    const int wave = threadIdx.x >> 6;
    const int l15 = lane & 15;
    const int khi = (lane >> 4) << 4;

    f32x4 acc[4][2];
#pragma unroll
    for (int i = 0; i < 4; ++i)
#pragma unroll
        for (int j = 0; j < 2; ++j)
            acc[i][j] = (f32x4){0.f, 0.f, 0.f, 0.f};

    for (int k0 = 0; k0 < K; k0 += 64) {
        if (wave < 2) stage_gl64(Ab + k0, lda, ldsA, wave, lane);
        stage_gl(Bb + k0, ldb, ldsB, wave, lane);
        __syncthreads();
#pragma unroll
        for (int kk = 0; kk < 2; ++kk) {
            const int kbyte = kk * 64 + khi;
            bf16x8 af[4], bfr[2];
#pragma unroll
            for (int i = 0; i < 4; ++i)
                af[i] = load_frag(ldsA, i * 16 + l15, kbyte);
#pragma unroll
            for (int j = 0; j < 2; ++j)
                bfr[j] = load_frag(ldsB, wave * 32 + j * 16 + l15, kbyte);
#pragma unroll
            for (int i = 0; i < 4; ++i)
#pragma unroll
                for (int j = 0; j < 2; ++j)
                    acc[i][j] = __builtin_amdgcn_mfma_f32_16x16x32_bf16(
                        af[i], bfr[j], acc[i][j], 0, 0, 0);
        }
        __syncthreads();
    }

    const int rbase = (lane >> 4) << 2;
#pragma unroll
    for (int i = 0; i < 4; ++i) {
#pragma unroll
        for (int r = 0; r < 4; ++r) {
            int row = m0 + i * 16 + rbase + r;
            float rA = 0.f, rB = 0.f;
            if (BIASM == BIAS_RANK2) {
                rA = p0[row];
                rB = p2[z * 768 + row];
            }
#pragma unroll
            for (int j = 0; j < 2; ++j) {
                int col = n0 + wave * 32 + j * 16 + l15;
                float v = acc[i][j][r] * scale;
                if (BIASM == BIAS_RANK2) v += rA * p1[z * vld1 + col] + rB * p3[col];
                if (BIASM == BIAS_RCOL)
                    v += bf2f(rsrc[(size_t)z * 688128 + (size_t)col * 896 + 768]);
                size_t off = (size_t)z * bsC + (size_t)row * ldc + col;
                if (OUT_BF16)
                    ((unsigned short*)C)[off] = f2bf(v);
                else
                    ((float*)C)[off] = v;
            }
        }
    }
}

// 64x64-tile GEMM (low-workgroup mid-chain dispatches).
template <int BIASM, bool OUT_BF16>
__global__ __launch_bounds__(256, 2) void gemm64_bf16(
    const unsigned short* __restrict__ A, const unsigned short* __restrict__ B,
    void* __restrict__ C,
    const float* __restrict__ p0, const float* __restrict__ p1,
    const float* __restrict__ p2, const float* __restrict__ p3,
    const unsigned short* __restrict__ rsrc,
    int K, int lda, int ldb, int ldc, long bsA, long bsB, long bsC,
    float scale, int vld1) {
    __shared__ __align__(16) char ldsA[8192];
    __shared__ __align__(16) char ldsB[8192];

    const unsigned gx = gridDim.x, gy = gridDim.y;
    const unsigned lin = blockIdx.x + gx * (blockIdx.y + gy * blockIdx.z);
    const unsigned wg = xcd_swizzle(lin, gx * gy * gridDim.z);
    const int bx = wg % gx;
    const int by = (wg / gx) % gy;
    const int z = wg / (gx * gy);

    const int m0 = by * 64;
    const int n0 = bx * 64;
    const unsigned short* Ab = A + (size_t)z * bsA + (size_t)m0 * lda;
    const unsigned short* Bb = B + (size_t)z * bsB + (size_t)n0 * ldb;

    const int lane = threadIdx.x & 63;
    const int wave = threadIdx.x >> 6;
    const int wr = wave >> 1;
    const int wc = wave & 1;
    const int l15 = lane & 15;
    const int khi = (lane >> 4) << 4;

    f32x4 acc[2][2];
#pragma unroll
    for (int i = 0; i < 2; ++i)
#pragma unroll
        for (int j = 0; j < 2; ++j)
            acc[i][j] = (f32x4){0.f, 0.f, 0.f, 0.f};

    gemm_core64(Ab, Bb, K, lda, ldb, ldsA, ldsB, wave, lane, wr, wc, l15, khi, acc);

    const int rbase = (lane >> 4) << 2;
#pragma unroll
    for (int i = 0; i < 2; ++i) {
#pragma unroll
        for (int r = 0; r < 4; ++r) {
            int row = m0 + wr * 32 + i * 16 + rbase + r;
            float rA = 0.f, rB = 0.f;
            if (BIASM == BIAS_RANK2) {
                rA = p0[row];
                rB = p2[z * 768 + row];
            }
#pragma unroll
            for (int j = 0; j < 2; ++j) {
                int col = n0 + wc * 32 + j * 16 + l15;
                float v = acc[i][j][r] * scale;
                if (BIASM == BIAS_RANK2) v += rA * p1[z * vld1 + col] + rB * p3[col];
                if (BIASM == BIAS_RCOL)
                    v += bf2f(rsrc[(size_t)z * 688128 + (size_t)col * 896 + 768]);
                size_t off = (size_t)z * bsC + (size_t)row * ldc + col;
                if (OUT_BF16)
                    ((unsigned short*)C)[off] = f2bf(v);
                else
                    ((float*)C)[off] = v;
            }
        }
    }
}

// z=0: Wqt+ rows 0..767 = Wq^T; z=1: Wkt = Wk^T; z=2: Wvb = bf16(Wv);
// z=3: Wqt+ row 768 = bq, rows 769..895 = 0; z=4: zero csum.
__global__ __launch_bounds__(256) void prep_w(const float* __restrict__ Wq,
                                              const float* __restrict__ Wk,
                                              const float* __restrict__ Wv,
                                              const float* __restrict__ bq,
                                              unsigned short* __restrict__ Wqt,
                                              unsigned short* __restrict__ Wkt,
                                              unsigned short* __restrict__ Wvb,
                                              float* __restrict__ csum) {
    const int mode = blockIdx.z;
    const int t = threadIdx.x;
    if (mode == 4) {
        if (blockIdx.x == 0 && blockIdx.y == 0) {
            float4 z4 = {0.f, 0.f, 0.f, 0.f};
            for (int i = t * 4; i < 3072; i += 1024) *(float4*)(csum + i) = z4;
        }
        return;
    }
    if (mode == 3) {
        if (blockIdx.y) return;
        int rr = 768 + (t >> 1);
        int c0 = blockIdx.x * 64 + (t & 1) * 32;
        unsigned short v[32] __attribute__((aligned(16)));
        if (rr == 768) {
#pragma unroll
            for (int j = 0; j < 32; ++j) v[j] = f2bf(bq[c0 + j]);
        } else {
#pragma unroll
            for (int j = 0; j < 32; ++j) v[j] = 0;
        }
        unsigned short* dst = Wqt + (size_t)rr * 768 + c0;
#pragma unroll
        for (int j = 0; j < 4; ++j) *(uint4*)(dst + j * 8) = *(uint4*)&v[j * 8];
        return;
    }
    __shared__ unsigned short tile[64 * 72];
    const float* src = mode == 0 ? Wq : (mode == 1 ? Wk : Wv);
    const int r0 = blockIdx.x * 64;
    const int c0 = blockIdx.y * 64;
    int r = t >> 2, cq = (t & 3) * 16;
    unsigned short v[16] __attribute__((aligned(16)));
    const float* s = src + (size_t)(r0 + r) * 768 + c0 + cq;
#pragma unroll
    for (int j = 0; j < 16; j += 4) {
        float4 f = *(const float4*)(s + j);
        v[j] = f2bf(f.x); v[j + 1] = f2bf(f.y);
        v[j + 2] = f2bf(f.z); v[j + 3] = f2bf(f.w);
    }
    if (mode == 2) {
        unsigned short* dst = Wvb + (size_t)(r0 + r) * 768 + c0 + cq;
        *(uint4*)dst = *(uint4*)&v[0];
        *(uint4*)(dst + 8) = *(uint4*)&v[8];
        return;
    }
    *(uint4*)&tile[r * 72 + cq] = *(uint4*)&v[0];
    *(uint4*)&tile[r * 72 + cq + 8] = *(uint4*)&v[8];
    __syncthreads();
    int dr = t >> 2, sq = (t & 3) * 16;
    unsigned short w[16] __attribute__((aligned(16)));
#pragma unroll
    for (int j = 0; j < 16; ++j) w[j] = tile[(sq + j) * 72 + dr];
    unsigned short* dst = (mode == 0 ? Wqt : Wkt) + (size_t)(c0 + dr) * 768 + r0 + sq;
    *(uint4*)dst = *(uint4*)&w[0];
    *(uint4*)(dst + 8) = *(uint4*)&w[8];
}

// Xbf [4][4096][768], Xt [4][768][4096], csum atomics.
__global__ __launch_bounds__(256) void prep_x(const float* __restrict__ X,
                                              unsigned short* __restrict__ Xbf,
                                              unsigned short* __restrict__ Xt,
                                              float* __restrict__ csum) {
    const int b = blockIdx.z;
    const int s0 = blockIdx.x * 64;
    const int t = threadIdx.x;
    __shared__ unsigned short tile[64 * 72];
    const int d0 = blockIdx.y * 64;
    const float* Xb = X + (size_t)b * 4096 * 768;
    unsigned short* XbfB = Xbf + (size_t)b * 4096 * 768;
    unsigned short* XtB = Xt + (size_t)b * 768 * 4096;
    {
        int r = t >> 2, cq = (t & 3) * 16;
        const float* src = Xb + (size_t)(s0 + r) * 768 + d0 + cq;
        unsigned short v[16] __attribute__((aligned(16)));
#pragma unroll
        for (int j = 0; j < 16; j += 4) {
            float4 f = *(const float4*)(src + j);
            v[j] = f2bf(f.x); v[j + 1] = f2bf(f.y);
            v[j + 2] = f2bf(f.z); v[j + 3] = f2bf(f.w);
        }
        unsigned short* dst = XbfB + (size_t)(s0 + r) * 768 + d0 + cq;
        *(uint4*)dst = *(uint4*)&v[0];
        *(uint4*)(dst + 8) = *(uint4*)&v[8];
        *(uint4*)&tile[r * 72 + cq] = *(uint4*)&v[0];
        *(uint4*)&tile[r * 72 + cq + 8] = *(uint4*)&v[8];
    }
    __syncthreads();
    {
        int dr = t >> 2, sq = (t & 3) * 16;
        unsigned short v[16] __attribute__((aligned(16)));
        float part = 0.f;
#pragma unroll
        for (int j = 0; j < 16; ++j) {
            unsigned short u = tile[(sq + j) * 72 + dr];
            v[j] = u;
            part += bf2f(u);
        }
        unsigned short* dst = XtB + (size_t)(d0 + dr) * 4096 + s0 + sq;
        *(uint4*)dst = *(uint4*)&v[0];
        *(uint4*)(dst + 8) = *(uint4*)&v[8];
        part += __shfl_down(part, 1);
        part += __shfl_down(part, 2);
        if ((t & 3) == 0) atomicAdd(&csum[b * 768 + d0 + dr], part);
    }
}

// Flat grid 3488:
//   wg < 2496: triangular 64x64 Gram partial tile (tile=wg%78, zz=wg/78;
//              b=zz>>3, split=zz&7, K=512) -> packed Gp [zz*78+tile][64][64]
//   wg < 3264: aux u/d2: id=wg-2496, b=id/192, row=(id%192)*4+wave
//   wg >=3264: c2p: row=(wg-3264)*4+wave (<896): c2p[row]=Wqt+[row].bk
__global__ __launch_bounds__(256, 2) void gram2(
    const unsigned short* __restrict__ Xt, unsigned short* __restrict__ Gp,
    const float* __restrict__ Wk, const float* __restrict__ Wv,
    const unsigned short* __restrict__ Wqt,
    const float* __restrict__ bk, const float* __restrict__ bv,
    const float* __restrict__ csum,
    float* __restrict__ u, float* __restrict__ d2, float* __restrict__ c2p) {
    const long PB = 3145728;
    const unsigned wg = xcd_swizzle(blockIdx.x, gridDim.x);
    const int t = threadIdx.x;
    const int lane = t & 63;
    const int wave = t >> 6;

    if (wg >= 3264) {  // c2p
        const int row = (wg - 3264) * 4 + wave;
        float a = 0.f;
        for (int e = lane * 4; e < 768; e += 256) {
            const unsigned short* qr = Wqt + (size_t)row * 768 + e;
            float4 b4 = *(const float4*)(bk + e);
            a += bf2f(qr[0]) * b4.x + bf2f(qr[1]) * b4.y +
                 bf2f(qr[2]) * b4.z + bf2f(qr[3]) * b4.w;
        }
#pragma unroll
        for (int off = 32; off; off >>= 1) a += __shfl_down(a, off);
        if (lane == 0) c2p[row] = a;
        return;
    }
    if (wg >= 2496) {  // u + d2
        const int id = wg - 2496;
        const int b = id / 192;
        const int row = (id % 192) * 4 + wave;
        const float* s = csum + b * 768;
        float aU = 0.f, aD = 0.f;
        for (int e = lane * 4; e < 768; e += 256) {
            float4 wk4 = *(const float4*)(Wk + (size_t)row * 768 + e);
            float4 wv4 = *(const float4*)(Wv + (size_t)row * 768 + e);
            float4 s4 = *(const float4*)(s + e);
            aU += wk4.x * s4.x + wk4.y * s4.y + wk4.z * s4.z + wk4.w * s4.w;
            aD += wv4.x * s4.x + wv4.y * s4.y + wv4.z * s4.z + wv4.w * s4.w;
        }
#pragma unroll
        for (int off = 32; off; off >>= 1) {
            aU += __shfl_down(aU, off);
            aD += __shfl_down(aD, off);
        }
        if (lane == 0) {
            u[b * 768 + row] = aU;
            d2[b * 768 + row] = SCALE * (aD + 4096.f * bv[row]);
        }
        return;
    }

    __shared__ __align__(16) char ldsA[8192];
    __shared__ __align__(16) char ldsB[8192];
    const int wr = wave >> 1;
    const int wc = wave & 1;
    const int l15 = lane & 15;
    const int khi = (lane >> 4) << 4;
    f32x4 acc[2][2];
#pragma unroll
    for (int i = 0; i < 2; ++i)
#pragma unroll
        for (int j = 0; j < 2; ++j)
            acc[i][j] = (f32x4){0.f, 0.f, 0.f, 0.f};
    const int rbase = (lane >> 4) << 2;

    const int tile = wg % 78;
    const int zz = wg / 78;
    const int b = zz >> 3;
    const int koff = (zz & 7) * 512;
    int tt = tile, tby = 0;
    while (tt >= 12 - tby) { tt -= 12 - tby; ++tby; }
    const int m0 = tby * 64;
    const int n0 = (tby + tt) * 64;
    const unsigned short* Ab = Xt + (size_t)b * PB + (size_t)m0 * 4096 + koff;
    const unsigned short* Bb = Xt + (size_t)b * PB + (size_t)n0 * 4096 + koff;
    gemm_core64(Ab, Bb, 512, 4096, 4096, ldsA, ldsB, wave, lane, wr, wc, l15, khi, acc);
    unsigned short* dst = Gp + ((size_t)zz * 78 + tile) * 4096;
#pragma unroll
    for (int i = 0; i < 2; ++i)
#pragma unroll
        for (int r = 0; r < 4; ++r) {
            int rloc = wr * 32 + i * 16 + rbase + r;
#pragma unroll
            for (int j = 0; j < 2; ++j) {
                int cloc = wc * 32 + j * 16 + l15;
                dst[(size_t)rloc * 64 + cloc] = f2bf(acc[i][j][r]);
            }
        }
}

// grid (344,4):
//   x<78: reduce Gp (8 splits) -> 64x64 G tile, mirror off-diag (y=b)
//   78<=x<302: c1p[b][row] = SCALE * Wqt+[row] . u_b   (row=(x-78)*4+wave)
//   x>=302: 64x64 P+ tile, id=(x-302)*4+y in [0,168): 14x12 tiles, K=768
__global__ __launch_bounds__(256, 2) void redvec2(
    const unsigned short* __restrict__ Gp, unsigned short* __restrict__ G,
    const unsigned short* __restrict__ Wqt, const unsigned short* __restrict__ Wkt,
    unsigned short* __restrict__ Pp,
    const float* __restrict__ u, float* __restrict__ c1p) {
    const int b = blockIdx.y;
    const int t = threadIdx.x;
    const int lane = t & 63;
    const int wave = t >> 6;
    if (blockIdx.x >= 302) {  // P+ 64x64, spread over all y
        __shared__ __align__(16) char ldsA[8192];
        __shared__ __align__(16) char ldsB[8192];
        const int id = (blockIdx.x - 302) * 4 + b;
        const int m0 = (id / 12) * 64;
        const int n0 = (id % 12) * 64;
        const int wr = wave >> 1;
        const int wc = wave & 1;
        const int l15 = lane & 15;
        const int khi = (lane >> 4) << 4;
        f32x4 acc[2][2];
#pragma unroll
        for (int i = 0; i < 2; ++i)
#pragma unroll
            for (int j = 0; j < 2; ++j)
                acc[i][j] = (f32x4){0.f, 0.f, 0.f, 0.f};
        gemm_core64(Wqt + (size_t)m0 * 768, Wkt + (size_t)n0 * 768,
                    768, 768, 768, ldsA, ldsB, wave, lane, wr, wc, l15, khi, acc);
        const int rbase = (lane >> 4) << 2;
#pragma unroll
        for (int i = 0; i < 2; ++i)
#pragma unroll
            for (int r = 0; r < 4; ++r) {
                int row = m0 + wr * 32 + i * 16 + rbase + r;
#pragma unroll
                for (int j = 0; j < 2; ++j) {
                    int col = n0 + wc * 32 + j * 16 + l15;
                    Pp[(size_t)row * 768 + col] = f2bf(acc[i][j][r]);
                }
            }
        return;
    }
    if (blockIdx.x >= 78) {  // c1p
        const int row = (blockIdx.x - 78) * 4 + wave;
        const float* ub = u + b * 768;
        float a = 0.f;
        for (int e = lane * 4; e < 768; e += 256) {
            const unsigned short* qr = Wqt + (size_t)row * 768 + e;
            float4 u4 = *(const float4*)(ub + e);
            a += bf2f(qr[0]) * u4.x + bf2f(qr[1]) * u4.y +
                 bf2f(qr[2]) * u4.z + bf2f(qr[3]) * u4.w;
        }
#pragma unroll
        for (int off = 32; off; off >>= 1) a += __shfl_down(a, off);
        if (lane == 0) c1p[b * 896 + row] = SCALE * a;
        return;
    }
    // reduce one 64x64 tile over 8 splits; mirror off-diagonal
    __shared__ unsigned short tl[64 * 72];
    const int tile = blockIdx.x;
    int tt = tile, tby = 0;
    while (tt >= 12 - tby) { tt -= 12 - tby; ++tby; }
    const int tbx = tby + tt;
    const int r = t >> 2;
    const int c0 = (t & 3) * 16;
    float acc[16];
#pragma unroll
    for (int j = 0; j < 16; ++j) acc[j] = 0.f;
    for (int sp = 0; sp < 8; ++sp) {
        const unsigned short* base =
            Gp + ((size_t)(b * 8 + sp) * 78 + tile) * 4096 + (size_t)r * 64 + c0;
#pragma unroll
        for (int j = 0; j < 2; ++j) {
            uint4 qv = *(const uint4*)(base + j * 8);
            const unsigned short* pv = (const unsigned short*)&qv;
#pragma unroll
            for (int k = 0; k < 8; ++k) acc[j * 8 + k] += bf2f(pv[k]);
        }
    }
    unsigned short v[16] __attribute__((aligned(16)));
#pragma unroll
    for (int j = 0; j < 16; ++j) v[j] = f2bf(acc[j]);
    unsigned short* dst = G + (size_t)b * 589824 +
                          (size_t)(tby * 64 + r) * 768 + tbx * 64 + c0;
    *(uint4*)dst = *(uint4*)&v[0];
    *(uint4*)(dst + 8) = *(uint4*)&v[8];
    if (tby != tbx) {
        *(uint4*)&tl[r * 72 + c0] = *(uint4*)&v[0];
        *(uint4*)&tl[r * 72 + c0 + 8] = *(uint4*)&v[8];
        __syncthreads();
        int dr = t >> 2, sq = (t & 3) * 16;
        unsigned short w[16] __attribute__((aligned(16)));
#pragma unroll
        for (int j = 0; j < 16; ++j) w[j] = tl[(sq + j) * 72 + dr];
        unsigned short* dm = G + (size_t)b * 589824 +
                             (size_t)(tbx * 64 + dr) * 768 + tby * 64 + sq;
        *(uint4*)dm = *(uint4*)&w[0];
        *(uint4*)(dm + 8) = *(uint4*)&w[8];
    }
}

extern "C" void kernel_launch(void* const* d_in, const int* in_sizes, int n_in,
                              void* d_out, int out_size, void* d_ws, size_t ws_size,
                              hipStream_t stream) {
    const float* x  = (const float*)d_in[0];
    const float* Wq = (const float*)d_in[1];
    const float* bq = (const float*)d_in[2];
    const float* Wk = (const float*)d_in[3];
    const float* bk = (const float*)d_in[4];
    const float* Wv = (const float*)d_in[5];
    const float* bv = (const float*)d_in[6];
    float* out = (float*)d_out;

    const long PB = 3145728;   // 4096*768
    const long DD = 589824;    // 768*768
    const long DA = 688128;    // 896*768

    unsigned short* ws  = (unsigned short*)d_ws;
    unsigned short* Xbf = ws;                       // 12582912
    unsigned short* Xt  = ws + 12582912;            // 12582912
    unsigned short* Pp  = ws + 25165824;            // 688128
    unsigned short* G   = ws + 25853952;            // 2359296
    unsigned short* Wqt = ws + 28213248;            // 688128 ([896][768])
    unsigned short* Wkt = ws + 28901376;            // 589824
    unsigned short* Wvb = ws + 29491200;            // 589824
    unsigned short* Gp  = ws + 30081024;            // 10223616 used (78*32 64x64)
    unsigned short* C1p = Gp;                       // overlay after redvec2
    unsigned short* At  = Gp + 2752512;             // 2752512
    float* fbase = (float*)(ws + 41091072);
    float* csum = fbase;                            // 3072
    float* u    = fbase + 3072;                     // 3072
    float* c1p  = fbase + 6144;                     // 3584
    float* c2p  = fbase + 9728;                     // 896
    float* d2   = fbase + 10624;                    // 3072

    dim3 blk(256, 1, 1);

    prep_w<<<dim3(12, 12, 5), blk, 0, stream>>>(Wq, Wk, Wv, bq, Wqt, Wkt, Wvb, csum);
    prep_x<<<dim3(64, 12, 4), blk, 0, stream>>>(x, Xbf, Xt, csum);

    // Gram tri 64x64 split-K partials (split=8, K=512) + u/d2 + c2p aux
    gram2<<<dim3(3488, 1, 1), blk, 0, stream>>>(Xt, Gp, Wk, Wv, Wqt, bk, bv,
                                                csum, u, d2, c2p);

    // reduce G (78 tiles) + c1p + P+ (64x64, 168 tiles over 4 y)
    redvec2<<<dim3(344, 4), blk, 0, stream>>>(Gp, G, Wqt, Wkt, Pp, u, c1p);

    // C1+ = P+ ⊠ G   [4][896][768]   (64x64 tiles: 672 wgs)
    gemm64_bf16<BIAS_NONE, true><<<dim3(12, 14, 4), blk, 0, stream>>>(
        Pp, G, C1p, nullptr, nullptr, nullptr, nullptr, nullptr,
        768, 768, 768, 768, 0, DD, DA, 1.0f, 0);

    // At = Wvb ⊠ C1+ (+rank2)   [4][768][896]   (64x64 tiles: 672 wgs)
    gemm64_bf16<BIAS_RANK2, true><<<dim3(14, 12, 4), blk, 0, stream>>>(
        Wvb, C1p, At, bv, c1p, d2, c2p, nullptr,
        768, 768, 768, 896, 0, DA, DA, SCALE, 896);

    // out = Xbf ⊠ At (K=768) + r epilogue (At col 768)  fp32
    // (64x128 rect: 1536 wgs, 6 blocks/CU; A traffic = 128-tile level)
    gemm_r64x128<BIAS_RCOL, false><<<dim3(6, 64, 4), blk, 0, stream>>>(
        Xbf, At, out, nullptr, nullptr, nullptr, nullptr, At,
        768, 768, 896, 768, PB, DA, PB, 1.0f, 0);
}

// Round 12
// 116.313 us; speedup vs baseline: 1.0078x; 1.0078x over previous
//
#include <hip/hip_runtime.h>

// out = X A + 1 r^T,  A = scale Wq^T (K^T V).  With G = X^T X, s = X^T 1:
//   K^T V = Wk G Wv^T + (Wk s) bv^T + bk (Wv s)^T + S bk bv^T
// Augment Wq+ = [Wq^T; bq^T; 0pad] (896x768) so r = col 768 of At.
//   memset csum; prep_all: Xbf/Xt/csum + Wqt+/Wkt/Wvb (merged prep, 3516 wgs)
//   gram2:  2496 tri 64x64 split-K Gram partial tiles (K=512, split=8)
//           + u/d2/c2p aux
//   redvec2: reduce Gp (8 splits, 78 64x64 tiles) -> G (mirror); c1p;
//            168 64x64 P+ tiles spread over all 4 y-slices
//   C1+ = P+ ⊠ G            [4][896][768]   (gemm64: 672 wgs)
//   At  = Wvb ⊠ C1+ (+rank2)[4][768][896]   (gemm64: 672 wgs)
//   out = Xbf ⊠ At (K=768) + At[col][768] epilogue  fp32 (gemm128: 768 wgs)
// GEMM: serial LDS loop (m97 structure), global_load_lds(16B) pre-swizzled
// source, XOR (r&7)<<4 reads, XCD-chunked bijective blockIdx swizzle.
// Tile-size model (R4..R11): serial-core dispatches are latency-bound until
// ~8 blocks/CU, then staging-BW-bound. 64x64 where occupancy <3 blocks/CU
// and operands L2-fit (gram2 R8 -15us, C1/At R6 -7us); 128x128 where grid
// >=3 blocks/CU (gemm3: R9 64sq +3us, R11 rect 64x128 +2.3us — rect tiles
// unbalance per-wave staging; retired).
// (R1: dbuf+counted-vmcnt regressed; R2: P+ move regressed; R3: fused
//  reduce 6x regression; R4/R5: split 4/16 regressed -> split=8 optimal.
//  R7: FAILED on gram2 grid arithmetic — aux budget must cover all rows.)

typedef __attribute__((ext_vector_type(8))) __bf16 bf16x8;
typedef __attribute__((ext_vector_type(4))) float f32x4;

#define SCALE 0.03608439182435161f

union FragU {
    uint4 q;
    bf16x8 f;
    unsigned short s[8];
};

__device__ __forceinline__ unsigned short f2bf(float x) {
    unsigned int u = __builtin_bit_cast(unsigned int, x);
    u = (u + 0x7fffu + ((u >> 16) & 1u)) >> 16;
    return (unsigned short)u;
}
__device__ __forceinline__ float bf2f(unsigned short u) {
    unsigned int v = ((unsigned int)u) << 16;
    return __builtin_bit_cast(float, v);
}

__device__ __forceinline__ unsigned xcd_swizzle(unsigned lin, unsigned nwg) {
    const unsigned q = nwg >> 3, rr8 = nwg & 7;
    const unsigned xcd = lin & 7, o = lin >> 3;
    return (xcd < rr8 ? xcd * (q + 1) : rr8 * (q + 1) + (xcd - rr8) * q) + o;
}

// 16KB staging for 128-row panel: wave w covers rows [w*32, w*32+32).
__device__ __forceinline__ void stage_gl(const unsigned short* __restrict__ srcRowBase,
                                         int ldElems, char* lds, int wave, int lane) {
#pragma unroll
    for (int p = 0; p < 4; ++p) {
        int slotbase = (wave * 4 + p) * 1024;
        int slot = slotbase + lane * 16;
        int r = slot >> 7;
        int cb = (slot & 127) ^ ((r & 7) << 4);
        const char* g = (const char*)(srcRowBase + (size_t)r * ldElems) + cb;
        __builtin_amdgcn_global_load_lds(
            (const __attribute__((address_space(1))) unsigned int*)g,
            (__attribute__((address_space(3))) unsigned int*)(lds + slotbase),
            16, 0, 0);
    }
}

// 8KB half-size staging: half in {0,1} covers rows [half*32, half*32+32).
__device__ __forceinline__ void stage_gl64(const unsigned short* __restrict__ srcRowBase,
                                           int ldElems, char* lds, int half, int lane) {
#pragma unroll
    for (int p = 0; p < 4; ++p) {
        int slotbase = (half * 4 + p) * 1024;
        int slot = slotbase + lane * 16;
        int r = slot >> 7;
        int cb = (slot & 127) ^ ((r & 7) << 4);
        const char* g = (const char*)(srcRowBase + (size_t)r * ldElems) + cb;
        __builtin_amdgcn_global_load_lds(
            (const __attribute__((address_space(1))) unsigned int*)g,
            (__attribute__((address_space(3))) unsigned int*)(lds + slotbase),
            16, 0, 0);
    }
}

__device__ __forceinline__ bf16x8 load_frag(const char* lds, int row, int kbyte) {
    int a = row * 128 + kbyte;
    a ^= (row & 7) << 4;
    FragU u;
    u.q = *(const uint4*)(lds + a);
    return u.f;
}

// 128x128 serial core (m97 structure): 4 waves as 2x2 of 64x64.
__device__ __forceinline__ void gemm_core(const unsigned short* __restrict__ Ab,
                                          const unsigned short* __restrict__ Bb,
                                          int K, int lda, int ldb,
                                          char* ldsA, char* ldsB,
                                          int wave, int lane, int wm, int wn,
                                          int l15, int khi, f32x4 (&acc)[4][4]) {
    for (int k0 = 0; k0 < K; k0 += 64) {
        stage_gl(Ab + k0, lda, ldsA, wave, lane);
        stage_gl(Bb + k0, ldb, ldsB, wave, lane);
        __syncthreads();
#pragma unroll
        for (int kk = 0; kk < 2; ++kk) {
            const int kbyte = kk * 64 + khi;
            bf16x8 af[4], bfr[4];
#pragma unroll
            for (int i = 0; i < 4; ++i)
                af[i] = load_frag(ldsA, wm * 64 + i * 16 + l15, kbyte);
#pragma unroll
            for (int j = 0; j < 4; ++j)
                bfr[j] = load_frag(ldsB, wn * 64 + j * 16 + l15, kbyte);
#pragma unroll
            for (int i = 0; i < 4; ++i)
#pragma unroll
                for (int j = 0; j < 4; ++j)
                    acc[i][j] = __builtin_amdgcn_mfma_f32_16x16x32_bf16(
                        af[i], bfr[j], acc[i][j], 0, 0, 0);
        }
        __syncthreads();
    }
}

// 64x64 serial core: 4 waves as 2x2 of 32x32; waves 0-1 stage A, 2-3 stage B.
__device__ __forceinline__ void gemm_core64(const unsigned short* __restrict__ Ab,
                                            const unsigned short* __restrict__ Bb,
                                            int K, int lda, int ldb,
                                            char* ldsA, char* ldsB,
                                            int wave, int lane, int wr, int wc,
                                            int l15, int khi, f32x4 (&acc)[2][2]) {
    for (int k0 = 0; k0 < K; k0 += 64) {
        if (wave < 2)
            stage_gl64(Ab + k0, lda, ldsA, wave, lane);
        else
            stage_gl64(Bb + k0, ldb, ldsB, wave - 2, lane);
        __syncthreads();
#pragma unroll
        for (int kk = 0; kk < 2; ++kk) {
            const int kbyte = kk * 64 + khi;
            bf16x8 af[2], bfr[2];
#pragma unroll
            for (int i = 0; i < 2; ++i)
                af[i] = load_frag(ldsA, wr * 32 + i * 16 + l15, kbyte);
#pragma unroll
            for (int j = 0; j < 2; ++j)
                bfr[j] = load_frag(ldsB, wc * 32 + j * 16 + l15, kbyte);
#pragma unroll
            for (int i = 0; i < 2; ++i)
#pragma unroll
                for (int j = 0; j < 2; ++j)
                    acc[i][j] = __builtin_amdgcn_mfma_f32_16x16x32_bf16(
                        af[i], bfr[j], acc[i][j], 0, 0, 0);
        }
        __syncthreads();
    }
}

enum { BIAS_NONE = 0, BIAS_RANK2 = 2, BIAS_RCOL = 3 };

// 128x128-tile GEMM (high-workgroup dispatches: gemm3).
template <int BIASM, bool OUT_BF16>
__global__ __launch_bounds__(256, 2) void gemm_bf16(
    const unsigned short* __restrict__ A, const unsigned short* __restrict__ B,
    void* __restrict__ C,
    const float* __restrict__ p0, const float* __restrict__ p1,
    const float* __restrict__ p2, const float* __restrict__ p3,
    const unsigned short* __restrict__ rsrc,
    int K, int lda, int ldb, int ldc, long bsA, long bsB, long bsC,
    float scale, int vld1) {
    __shared__ __align__(16) char ldsA[16384];
    __shared__ __align__(16) char ldsB[16384];

    const unsigned gx = gridDim.x, gy = gridDim.y;
    const unsigned lin = blockIdx.x + gx * (blockIdx.y + gy * blockIdx.z);
    const unsigned wg = xcd_swizzle(lin, gx * gy * gridDim.z);
    const int bx = wg % gx;
    const int by = (wg / gx) % gy;
    const int z = wg / (gx * gy);

    const int m0 = by * 128;
    const int n0 = bx * 128;
    const unsigned short* Ab = A + (size_t)z * bsA + (size_t)m0 * lda;
    const unsigned short* Bb = B + (size_t)z * bsB + (size_t)n0 * ldb;

    const int lane = threadIdx.x & 63;
    const int wave = threadIdx.x >> 6;
    const int wm = wave >> 1;
    const int wn = wave & 1;
    const int l15 = lane & 15;
    const int khi = (lane >> 4) << 4;

    f32x4 acc[4][4];
#pragma unroll
    for (int i = 0; i < 4; ++i)
#pragma unroll
        for (int j = 0; j < 4; ++j)
            acc[i][j] = (f32x4){0.f, 0.f, 0.f, 0.f};

    gemm_core(Ab, Bb, K, lda, ldb, ldsA, ldsB, wave, lane, wm, wn, l15, khi, acc);

    const int rbase = (lane >> 4) << 2;
#pragma unroll
    for (int i = 0; i < 4; ++i) {
#pragma unroll
        for (int r = 0; r < 4; ++r) {
            int row = m0 + wm * 64 + i * 16 + rbase + r;
            float rA = 0.f, rB = 0.f;
            if (BIASM == BIAS_RANK2) {
                rA = p0[row];
                rB = p2[z * 768 + row];
            }
#pragma unroll
            for (int j = 0; j < 4; ++j) {
                int col = n0 + wn * 64 + j * 16 + l15;
                float v = acc[i][j][r] * scale;
                if (BIASM == BIAS_RANK2) v += rA * p1[z * vld1 + col] + rB * p3[col];
                if (BIASM == BIAS_RCOL)
                    v += bf2f(rsrc[(size_t)z * 688128 + (size_t)col * 896 + 768]);
                size_t off = (size_t)z * bsC + (size_t)row * ldc + col;
                if (OUT_BF16)
                    ((unsigned short*)C)[off] = f2bf(v);
                else
                    ((float*)C)[off] = v;
            }
        }
    }
}

// 64x64-tile GEMM (low-workgroup mid-chain dispatches).
template <int BIASM, bool OUT_BF16>
__global__ __launch_bounds__(256, 2) void gemm64_bf16(
    const unsigned short* __restrict__ A, const unsigned short* __restrict__ B,
    void* __restrict__ C,
    const float* __restrict__ p0, const float* __restrict__ p1,
    const float* __restrict__ p2, const float* __restrict__ p3,
    const unsigned short* __restrict__ rsrc,
    int K, int lda, int ldb, int ldc, long bsA, long bsB, long bsC,
    float scale, int vld1) {
    __shared__ __align__(16) char ldsA[8192];
    __shared__ __align__(16) char ldsB[8192];

    const unsigned gx = gridDim.x, gy = gridDim.y;
    const unsigned lin = blockIdx.x + gx * (blockIdx.y + gy * blockIdx.z);
    const unsigned wg = xcd_swizzle(lin, gx * gy * gridDim.z);
    const int bx = wg % gx;
    const int by = (wg / gx) % gy;
    const int z = wg / (gx * gy);

    const int m0 = by * 64;
    const int n0 = bx * 64;
    const unsigned short* Ab = A + (size_t)z * bsA + (size_t)m0 * lda;
    const unsigned short* Bb = B + (size_t)z * bsB + (size_t)n0 * ldb;

    const int lane = threadIdx.x & 63;
    const int wave = threadIdx.x >> 6;
    const int wr = wave >> 1;
    const int wc = wave & 1;
    const int l15 = lane & 15;
    const int khi = (lane >> 4) << 4;

    f32x4 acc[2][2];
#pragma unroll
    for (int i = 0; i < 2; ++i)
#pragma unroll
        for (int j = 0; j < 2; ++j)
            acc[i][j] = (f32x4){0.f, 0.f, 0.f, 0.f};

    gemm_core64(Ab, Bb, K, lda, ldb, ldsA, ldsB, wave, lane, wr, wc, l15, khi, acc);

    const int rbase = (lane >> 4) << 2;
#pragma unroll
    for (int i = 0; i < 2; ++i) {
#pragma unroll
        for (int r = 0; r < 4; ++r) {
            int row = m0 + wr * 32 + i * 16 + rbase + r;
            float rA = 0.f, rB = 0.f;
            if (BIASM == BIAS_RANK2) {
                rA = p0[row];
                rB = p2[z * 768 + row];
            }
#pragma unroll
            for (int j = 0; j < 2; ++j) {
                int col = n0 + wc * 32 + j * 16 + l15;
                float v = acc[i][j][r] * scale;
                if (BIASM == BIAS_RANK2) v += rA * p1[z * vld1 + col] + rB * p3[col];
                if (BIASM == BIAS_RCOL)
                    v += bf2f(rsrc[(size_t)z * 688128 + (size_t)col * 896 + 768]);
                size_t off = (size_t)z * bsC + (size_t)row * ldc + col;
                if (OUT_BF16)
                    ((unsigned short*)C)[off] = f2bf(v);
                else
                    ((float*)C)[off] = v;
            }
        }
    }
}

// Merged prep, flat grid 3516 (csum pre-zeroed by hipMemsetAsync):
//   wg < 3072: prep_x block: b=wg/768, rem=wg%768, s0=(rem%64)*64,
//              d0=(rem/64)*64 -> Xbf + Xt + csum atomics
//   else id=wg-3072:
//     id < 144: Wqt = Wq^T tile (r0=(id%12)*64, c0=(id/12)*64)
//     id < 288: Wkt = Wk^T tile
//     id < 432: Wvb = bf16(Wv) tile
//     id < 444: Wqt+ rows 768..895 (row 768 = bq, rest 0), c-block id-432
__global__ __launch_bounds__(256) void prep_all(
    const float* __restrict__ X,
    const float* __restrict__ Wq, const float* __restrict__ Wk,
    const float* __restrict__ Wv, const float* __restrict__ bq,
    unsigned short* __restrict__ Xbf, unsigned short* __restrict__ Xt,
    unsigned short* __restrict__ Wqt, unsigned short* __restrict__ Wkt,
    unsigned short* __restrict__ Wvb, float* __restrict__ csum) {
    const unsigned wg = blockIdx.x;
    const int t = threadIdx.x;
    __shared__ unsigned short tile[64 * 72];

    if (wg >= 3072) {
        const int id = wg - 3072;
        if (id >= 432) {  // Wqt+ tail rows 768..895
            int rr = 768 + (t >> 1);
            int c0 = (id - 432) * 64 + (t & 1) * 32;
            unsigned short v[32] __attribute__((aligned(16)));
            if (rr == 768) {
#pragma unroll
                for (int j = 0; j < 32; ++j) v[j] = f2bf(bq[c0 + j]);
            } else {
#pragma unroll
                for (int j = 0; j < 32; ++j) v[j] = 0;
            }
            unsigned short* dst = Wqt + (size_t)rr * 768 + c0;
#pragma unroll
            for (int j = 0; j < 4; ++j) *(uint4*)(dst + j * 8) = *(uint4*)&v[j * 8];
            return;
        }
        const int mode = id / 144;  // 0=Wq^T, 1=Wk^T, 2=Wvb
        const int sub = id % 144;
        const int r0 = (sub % 12) * 64;
        const int c0 = (sub / 12) * 64;
        const float* src = mode == 0 ? Wq : (mode == 1 ? Wk : Wv);
        int r = t >> 2, cq = (t & 3) * 16;
        unsigned short v[16] __attribute__((aligned(16)));
        const float* s = src + (size_t)(r0 + r) * 768 + c0 + cq;
#pragma unroll
        for (int j = 0; j < 16; j += 4) {
            float4 f = *(const float4*)(s + j);
            v[j] = f2bf(f.x); v[j + 1] = f2bf(f.y);
            v[j + 2] = f2bf(f.z); v[j + 3] = f2bf(f.w);
        }
        if (mode == 2) {
            unsigned short* dst = Wvb + (size_t)(r0 + r) * 768 + c0 + cq;
            *(uint4*)dst = *(uint4*)&v[0];
            *(uint4*)(dst + 8) = *(uint4*)&v[8];
            return;
        }
        *(uint4*)&tile[r * 72 + cq] = *(uint4*)&v[0];
        *(uint4*)&tile[r * 72 + cq + 8] = *(uint4*)&v[8];
        __syncthreads();
        int dr = t >> 2, sq = (t & 3) * 16;
        unsigned short w[16] __attribute__((aligned(16)));
#pragma unroll
        for (int j = 0; j < 16; ++j) w[j] = tile[(sq + j) * 72 + dr];
        unsigned short* dst =
            (mode == 0 ? Wqt : Wkt) + (size_t)(c0 + dr) * 768 + r0 + sq;
        *(uint4*)dst = *(uint4*)&w[0];
        *(uint4*)(dst + 8) = *(uint4*)&w[8];
        return;
    }

    // prep_x part
    const int b = wg / 768;
    const int rem = wg % 768;
    const int s0 = (rem % 64) * 64;
    const int d0 = (rem / 64) * 64;
    const float* Xb = X + (size_t)b * 4096 * 768;
    unsigned short* XbfB = Xbf + (size_t)b * 4096 * 768;
    unsigned short* XtB = Xt + (size_t)b * 768 * 4096;
    {
        int r = t >> 2, cq = (t & 3) * 16;
        const float* src = Xb + (size_t)(s0 + r) * 768 + d0 + cq;
        unsigned short v[16] __attribute__((aligned(16)));
#pragma unroll
        for (int j = 0; j < 16; j += 4) {
            float4 f = *(const float4*)(src + j);
            v[j] = f2bf(f.x); v[j + 1] = f2bf(f.y);
            v[j + 2] = f2bf(f.z); v[j + 3] = f2bf(f.w);
        }
        unsigned short* dst = XbfB + (size_t)(s0 + r) * 768 + d0 + cq;
        *(uint4*)dst = *(uint4*)&v[0];
        *(uint4*)(dst + 8) = *(uint4*)&v[8];
        *(uint4*)&tile[r * 72 + cq] = *(uint4*)&v[0];
        *(uint4*)&tile[r * 72 + cq + 8] = *(uint4*)&v[8];
    }
    __syncthreads();
    {
        int dr = t >> 2, sq = (t & 3) * 16;
        unsigned short v[16] __attribute__((aligned(16)));
        float part = 0.f;
#pragma unroll
        for (int j = 0; j < 16; ++j) {
            unsigned short u = tile[(sq + j) * 72 + dr];
            v[j] = u;
            part += bf2f(u);
        }
        unsigned short* dst = XtB + (size_t)(d0 + dr) * 4096 + s0 + sq;
        *(uint4*)dst = *(uint4*)&v[0];
        *(uint4*)(dst + 8) = *(uint4*)&v[8];
        part += __shfl_down(part, 1);
        part += __shfl_down(part, 2);
        if ((t & 3) == 0) atomicAdd(&csum[b * 768 + d0 + dr], part);
    }
}

// Flat grid 3488:
//   wg < 2496: triangular 64x64 Gram partial tile (tile=wg%78, zz=wg/78;
//              b=zz>>3, split=zz&7, K=512) -> packed Gp [zz*78+tile][64][64]
//   wg < 3264: aux u/d2: id=wg-2496, b=id/192, row=(id%192)*4+wave
//   wg >=3264: c2p: row=(wg-3264)*4+wave (<896): c2p[row]=Wqt+[row].bk
__global__ __launch_bounds__(256, 2) void gram2(
    const unsigned short* __restrict__ Xt, unsigned short* __restrict__ Gp,
    const float* __restrict__ Wk, const float* __restrict__ Wv,
    const unsigned short* __restrict__ Wqt,
    const float* __restrict__ bk, const float* __restrict__ bv,
    const float* __restrict__ csum,
    float* __restrict__ u, float* __restrict__ d2, float* __restrict__ c2p) {
    const long PB = 3145728;
    const unsigned wg = xcd_swizzle(blockIdx.x, gridDim.x);
    const int t = threadIdx.x;
    const int lane = t & 63;
    const int wave = t >> 6;

    if (wg >= 3264) {  // c2p
        const int row = (wg - 3264) * 4 + wave;
        float a = 0.f;
        for (int e = lane * 4; e < 768; e += 256) {
            const unsigned short* qr = Wqt + (size_t)row * 768 + e;
            float4 b4 = *(const float4*)(bk + e);
            a += bf2f(qr[0]) * b4.x + bf2f(qr[1]) * b4.y +
                 bf2f(qr[2]) * b4.z + bf2f(qr[3]) * b4.w;
        }
#pragma unroll
        for (int off = 32; off; off >>= 1) a += __shfl_down(a, off);
        if (lane == 0) c2p[row] = a;
        return;
    }
    if (wg >= 2496) {  // u + d2
        const int id = wg - 2496;
        const int b = id / 192;
        const int row = (id % 192) * 4 + wave;
        const float* s = csum + b * 768;
        float aU = 0.f, aD = 0.f;
        for (int e = lane * 4; e < 768; e += 256) {
            float4 wk4 = *(const float4*)(Wk + (size_t)row * 768 + e);
            float4 wv4 = *(const float4*)(Wv + (size_t)row * 768 + e);
            float4 s4 = *(const float4*)(s + e);
            aU += wk4.x * s4.x + wk4.y * s4.y + wk4.z * s4.z + wk4.w * s4.w;
            aD += wv4.x * s4.x + wv4.y * s4.y + wv4.z * s4.z + wv4.w * s4.w;
        }
#pragma unroll
        for (int off = 32; off; off >>= 1) {
            aU += __shfl_down(aU, off);
            aD += __shfl_down(aD, off);
        }
        if (lane == 0) {
            u[b * 768 + row] = aU;
            d2[b * 768 + row] = SCALE * (aD + 4096.f * bv[row]);
        }
        return;
    }

    __shared__ __align__(16) char ldsA[8192];
    __shared__ __align__(16) char ldsB[8192];
    const int wr = wave >> 1;
    const int wc = wave & 1;
    const int l15 = lane & 15;
    const int khi = (lane >> 4) << 4;
    f32x4 acc[2][2];
#pragma unroll
    for (int i = 0; i < 2; ++i)
#pragma unroll
        for (int j = 0; j < 2; ++j)
            acc[i][j] = (f32x4){0.f, 0.f, 0.f, 0.f};
    const int rbase = (lane >> 4) << 2;

    const int tile = wg % 78;
    const int zz = wg / 78;
    const int b = zz >> 3;
    const int koff = (zz & 7) * 512;
    int tt = tile, tby = 0;
    while (tt >= 12 - tby) { tt -= 12 - tby; ++tby; }
    const int m0 = tby * 64;
    const int n0 = (tby + tt) * 64;
    const unsigned short* Ab = Xt + (size_t)b * PB + (size_t)m0 * 4096 + koff;
    const unsigned short* Bb = Xt + (size_t)b * PB + (size_t)n0 * 4096 + koff;
    gemm_core64(Ab, Bb, 512, 4096, 4096, ldsA, ldsB, wave, lane, wr, wc, l15, khi, acc);
    unsigned short* dst = Gp + ((size_t)zz * 78 + tile) * 4096;
#pragma unroll
    for (int i = 0; i < 2; ++i)
#pragma unroll
        for (int r = 0; r < 4; ++r) {
            int rloc = wr * 32 + i * 16 + rbase + r;
#pragma unroll
            for (int j = 0; j < 2; ++j) {
                int cloc = wc * 32 + j * 16 + l15;
                dst[(size_t)rloc * 64 + cloc] = f2bf(acc[i][j][r]);
            }
        }
}

// grid (344,4):
//   x<78: reduce Gp (8 splits) -> 64x64 G tile, mirror off-diag (y=b)
//   78<=x<302: c1p[b][row] = SCALE * Wqt+[row] . u_b   (row=(x-78)*4+wave)
//   x>=302: 64x64 P+ tile, id=(x-302)*4+y in [0,168): 14x12 tiles, K=768
__global__ __launch_bounds__(256, 2) void redvec2(
    const unsigned short* __restrict__ Gp, unsigned short* __restrict__ G,
    const unsigned short* __restrict__ Wqt, const unsigned short* __restrict__ Wkt,
    unsigned short* __restrict__ Pp,
    const float* __restrict__ u, float* __restrict__ c1p) {
    const int b = blockIdx.y;
    const int t = threadIdx.x;
    const int lane = t & 63;
    const int wave = t >> 6;
    if (blockIdx.x >= 302) {  // P+ 64x64, spread over all y
        __shared__ __align__(16) char ldsA[8192];
        __shared__ __align__(16) char ldsB[8192];
        const int id = (blockIdx.x - 302) * 4 + b;
        const int m0 = (id / 12) * 64;
        const int n0 = (id % 12) * 64;
        const int wr = wave >> 1;
        const int wc = wave & 1;
        const int l15 = lane & 15;
        const int khi = (lane >> 4) << 4;
        f32x4 acc[2][2];
#pragma unroll
        for (int i = 0; i < 2; ++i)
#pragma unroll
            for (int j = 0; j < 2; ++j)
                acc[i][j] = (f32x4){0.f, 0.f, 0.f, 0.f};
        gemm_core64(Wqt + (size_t)m0 * 768, Wkt + (size_t)n0 * 768,
                    768, 768, 768, ldsA, ldsB, wave, lane, wr, wc, l15, khi, acc);
        const int rbase = (lane >> 4) << 2;
#pragma unroll
        for (int i = 0; i < 2; ++i)
#pragma unroll
            for (int r = 0; r < 4; ++r) {
                int row = m0 + wr * 32 + i * 16 + rbase + r;
#pragma unroll
                for (int j = 0; j < 2; ++j) {
                    int col = n0 + wc * 32 + j * 16 + l15;
                    Pp[(size_t)row * 768 + col] = f2bf(acc[i][j][r]);
                }
            }
        return;
    }
    if (blockIdx.x >= 78) {  // c1p
        const int row = (blockIdx.x - 78) * 4 + wave;
        const float* ub = u + b * 768;
        float a = 0.f;
        for (int e = lane * 4; e < 768; e += 256) {
            const unsigned short* qr = Wqt + (size_t)row * 768 + e;
            float4 u4 = *(const float4*)(ub + e);
            a += bf2f(qr[0]) * u4.x + bf2f(qr[1]) * u4.y +
                 bf2f(qr[2]) * u4.z + bf2f(qr[3]) * u4.w;
        }
#pragma unroll
        for (int off = 32; off; off >>= 1) a += __shfl_down(a, off);
        if (lane == 0) c1p[b * 896 + row] = SCALE * a;
        return;
    }
    // reduce one 64x64 tile over 8 splits; mirror off-diagonal
    __shared__ unsigned short tl[64 * 72];
    const int tile = blockIdx.x;
    int tt = tile, tby = 0;
    while (tt >= 12 - tby) { tt -= 12 - tby; ++tby; }
    const int tbx = tby + tt;
    const int r = t >> 2;
    const int c0 = (t & 3) * 16;
    float acc[16];
#pragma unroll
    for (int j = 0; j < 16; ++j) acc[j] = 0.f;
    for (int sp = 0; sp < 8; ++sp) {
        const unsigned short* base =
            Gp + ((size_t)(b * 8 + sp) * 78 + tile) * 4096 + (size_t)r * 64 + c0;
#pragma unroll
        for (int j = 0; j < 2; ++j) {
            uint4 qv = *(const uint4*)(base + j * 8);
            const unsigned short* pv = (const unsigned short*)&qv;
#pragma unroll
            for (int k = 0; k < 8; ++k) acc[j * 8 + k] += bf2f(pv[k]);
        }
    }
    unsigned short v[16] __attribute__((aligned(16)));
#pragma unroll
    for (int j = 0; j < 16; ++j) v[j] = f2bf(acc[j]);
    unsigned short* dst = G + (size_t)b * 589824 +
                          (size_t)(tby * 64 + r) * 768 + tbx * 64 + c0;
    *(uint4*)dst = *(uint4*)&v[0];
    *(uint4*)(dst + 8) = *(uint4*)&v[8];
    if (tby != tbx) {
        *(uint4*)&tl[r * 72 + c0] = *(uint4*)&v[0];
        *(uint4*)&tl[r * 72 + c0 + 8] = *(uint4*)&v[8];
        __syncthreads();
        int dr = t >> 2, sq = (t & 3) * 16;
        unsigned short w[16] __attribute__((aligned(16)));
#pragma unroll
        for (int j = 0; j < 16; ++j) w[j] = tl[(sq + j) * 72 + dr];
        unsigned short* dm = G + (size_t)b * 589824 +
                             (size_t)(tbx * 64 + dr) * 768 + tby * 64 + sq;
        *(uint4*)dm = *(uint4*)&w[0];
        *(uint4*)(dm + 8) = *(uint4*)&w[8];
    }
}

extern "C" void kernel_launch(void* const* d_in, const int* in_sizes, int n_in,
                              void* d_out, int out_size, void* d_ws, size_t ws_size,
                              hipStream_t stream) {
    const float* x  = (const float*)d_in[0];
    const float* Wq = (const float*)d_in[1];
    const float* bq = (const float*)d_in[2];
    const float* Wk = (const float*)d_in[3];
    const float* bk = (const float*)d_in[4];
    const float* Wv = (const float*)d_in[5];
    const float* bv = (const float*)d_in[6];
    float* out = (float*)d_out;

    const long PB = 3145728;   // 4096*768
    const long DD = 589824;    // 768*768
    const long DA = 688128;    // 896*768

    unsigned short* ws  = (unsigned short*)d_ws;
    unsigned short* Xbf = ws;                       // 12582912
    unsigned short* Xt  = ws + 12582912;            // 12582912
    unsigned short* Pp  = ws + 25165824;            // 688128
    unsigned short* G   = ws + 25853952;            // 2359296
    unsigned short* Wqt = ws + 28213248;            // 688128 ([896][768])
    unsigned short* Wkt = ws + 28901376;            // 589824
    unsigned short* Wvb = ws + 29491200;            // 589824
    unsigned short* Gp  = ws + 30081024;            // 10223616 used (78*32 64x64)
    unsigned short* C1p = Gp;                       // overlay after redvec2
    unsigned short* At  = Gp + 2752512;             // 2752512
    float* fbase = (float*)(ws + 41091072);
    float* csum = fbase;                            // 3072
    float* u    = fbase + 3072;                     // 3072
    float* c1p  = fbase + 6144;                     // 3584
    float* c2p  = fbase + 9728;                     // 896
    float* d2   = fbase + 10624;                    // 3072

    dim3 blk(256, 1, 1);

    // zero csum (stream-ordered; replaces prep_w mode-4)
    hipMemsetAsync(csum, 0, 3072 * sizeof(float), stream);

    // merged prep: Xbf/Xt/csum + Wqt+/Wkt/Wvb
    prep_all<<<dim3(3516, 1, 1), blk, 0, stream>>>(x, Wq, Wk, Wv, bq,
                                                   Xbf, Xt, Wqt, Wkt, Wvb, csum);

    // Gram tri 64x64 split-K partials (split=8, K=512) + u/d2 + c2p aux
    gram2<<<dim3(3488, 1, 1), blk, 0, stream>>>(Xt, Gp, Wk, Wv, Wqt, bk, bv,
                                                csum, u, d2, c2p);

    // reduce G (78 tiles) + c1p + P+ (64x64, 168 tiles over 4 y)
    redvec2<<<dim3(344, 4), blk, 0, stream>>>(Gp, G, Wqt, Wkt, Pp, u, c1p);

    // C1+ = P+ ⊠ G   [4][896][768]   (64x64 tiles: 672 wgs)
    gemm64_bf16<BIAS_NONE, true><<<dim3(12, 14, 4), blk, 0, stream>>>(
        Pp, G, C1p, nullptr, nullptr, nullptr, nullptr, nullptr,
        768, 768, 768, 768, 0, DD, DA, 1.0f, 0);

    // At = Wvb ⊠ C1+ (+rank2)   [4][768][896]   (64x64 tiles: 672 wgs)
    gemm64_bf16<BIAS_RANK2, true><<<dim3(14, 12, 4), blk, 0, stream>>>(
        Wvb, C1p, At, bv, c1p, d2, c2p, nullptr,
        768, 768, 768, 896, 0, DA, DA, SCALE, 896);

    // out = Xbf ⊠ At (K=768) + r epilogue (At col 768)  fp32 (128x128: 768 wgs)
    gemm_bf16<BIAS_RCOL, false><<<dim3(6, 32, 4), blk, 0, stream>>>(
        Xbf, At, out, nullptr, nullptr, nullptr, nullptr, At,
        768, 768, 896, 768, PB, DA, PB, 1.0f, 0);
}

// Round 13
// 114.236 us; speedup vs baseline: 1.0261x; 1.0182x over previous
//
#include <hip/hip_runtime.h>

// out = X A + 1 r^T,  A = scale Wq^T (K^T V).  With G = X^T X, s = X^T 1:
//   K^T V = Wk G Wv^T + (Wk s) bv^T + bk (Wv s)^T + S bk bv^T
// Augment Wq+ = [Wq^T; bq^T; 0pad] (896x768) so r = col 768 of At.
//   prep_w: Wqt+/Wkt/Wvb (bf16) + zero csum
//   prep_x: Xbf [4][4096][768], Xt [4][768][4096], csum atomics
//   gram2:  2496 tri 64x64 split-K Gram partial tiles (K=512, split=8)
//           + u/d2/c2p aux
//   redvec2: reduce Gp (8 splits, 78 64x64 tiles) -> G (mirror); c1p;
//            168 64x64 P+ tiles spread over all 4 y-slices
//   C1+ = P+ ⊠ G            [4][896][768]   (gemm64: 672 wgs)
//   At  = Wvb ⊠ C1+ (+rank2)[4][768][896]   (gemm64: 672 wgs)
//   out = Xbf ⊠ At (K=768) + At[col][768] epilogue  fp32 (gemm128: 768 wgs)
// GEMM: serial LDS loop (m97 structure), global_load_lds(16B) pre-swizzled
// source, XOR (r&7)<<4 reads, XCD-chunked bijective blockIdx swizzle.
// Tile-size model (R4..R12): serial-core dispatches are latency-bound until
// ~8 blocks/CU, then staging-BW-bound. 64x64 where occupancy <3 blocks/CU
// and operands L2-fit (gram2 R8 -15us, C1/At R6 -7us); 128x128 where grid
// >=3 blocks/CU (gemm3: R9 64sq +3us, R11 rect 64x128 +2.3us). R12 prep
// merge neutral. This is the measured-best (R10) configuration: 114.9us.
// (R1: dbuf+counted-vmcnt regressed; R2: P+ move regressed; R3: fused
//  reduce 6x regression; R4/R5: split 4/16 regressed -> split=8 optimal.
//  R7: FAILED on gram2 grid arithmetic — aux budget must cover all rows.)

typedef __attribute__((ext_vector_type(8))) __bf16 bf16x8;
typedef __attribute__((ext_vector_type(4))) float f32x4;

#define SCALE 0.03608439182435161f

union FragU {
    uint4 q;
    bf16x8 f;
    unsigned short s[8];
};

__device__ __forceinline__ unsigned short f2bf(float x) {
    unsigned int u = __builtin_bit_cast(unsigned int, x);
    u = (u + 0x7fffu + ((u >> 16) & 1u)) >> 16;
    return (unsigned short)u;
}
__device__ __forceinline__ float bf2f(unsigned short u) {
    unsigned int v = ((unsigned int)u) << 16;
    return __builtin_bit_cast(float, v);
}

__device__ __forceinline__ unsigned xcd_swizzle(unsigned lin, unsigned nwg) {
    const unsigned q = nwg >> 3, rr8 = nwg & 7;
    const unsigned xcd = lin & 7, o = lin >> 3;
    return (xcd < rr8 ? xcd * (q + 1) : rr8 * (q + 1) + (xcd - rr8) * q) + o;
}

// 16KB staging for 128-row panel: wave w covers rows [w*32, w*32+32).
__device__ __forceinline__ void stage_gl(const unsigned short* __restrict__ srcRowBase,
                                         int ldElems, char* lds, int wave, int lane) {
#pragma unroll
    for (int p = 0; p < 4; ++p) {
        int slotbase = (wave * 4 + p) * 1024;
        int slot = slotbase + lane * 16;
        int r = slot >> 7;
        int cb = (slot & 127) ^ ((r & 7) << 4);
        const char* g = (const char*)(srcRowBase + (size_t)r * ldElems) + cb;
        __builtin_amdgcn_global_load_lds(
            (const __attribute__((address_space(1))) unsigned int*)g,
            (__attribute__((address_space(3))) unsigned int*)(lds + slotbase),
            16, 0, 0);
    }
}

// 8KB half-size staging: half in {0,1} covers rows [half*32, half*32+32).
__device__ __forceinline__ void stage_gl64(const unsigned short* __restrict__ srcRowBase,
                                           int ldElems, char* lds, int half, int lane) {
#pragma unroll
    for (int p = 0; p < 4; ++p) {
        int slotbase = (half * 4 + p) * 1024;
        int slot = slotbase + lane * 16;
        int r = slot >> 7;
        int cb = (slot & 127) ^ ((r & 7) << 4);
        const char* g = (const char*)(srcRowBase + (size_t)r * ldElems) + cb;
        __builtin_amdgcn_global_load_lds(
            (const __attribute__((address_space(1))) unsigned int*)g,
            (__attribute__((address_space(3))) unsigned int*)(lds + slotbase),
            16, 0, 0);
    }
}

__device__ __forceinline__ bf16x8 load_frag(const char* lds, int row, int kbyte) {
    int a = row * 128 + kbyte;
    a ^= (row & 7) << 4;
    FragU u;
    u.q = *(const uint4*)(lds + a);
    return u.f;
}

// 128x128 serial core (m97 structure): 4 waves as 2x2 of 64x64.
__device__ __forceinline__ void gemm_core(const unsigned short* __restrict__ Ab,
                                          const unsigned short* __restrict__ Bb,
                                          int K, int lda, int ldb,
                                          char* ldsA, char* ldsB,
                                          int wave, int lane, int wm, int wn,
                                          int l15, int khi, f32x4 (&acc)[4][4]) {
    for (int k0 = 0; k0 < K; k0 += 64) {
        stage_gl(Ab + k0, lda, ldsA, wave, lane);
        stage_gl(Bb + k0, ldb, ldsB, wave, lane);
        __syncthreads();
#pragma unroll
        for (int kk = 0; kk < 2; ++kk) {
            const int kbyte = kk * 64 + khi;
            bf16x8 af[4], bfr[4];
#pragma unroll
            for (int i = 0; i < 4; ++i)
                af[i] = load_frag(ldsA, wm * 64 + i * 16 + l15, kbyte);
#pragma unroll
            for (int j = 0; j < 4; ++j)
                bfr[j] = load_frag(ldsB, wn * 64 + j * 16 + l15, kbyte);
#pragma unroll
            for (int i = 0; i < 4; ++i)
#pragma unroll
                for (int j = 0; j < 4; ++j)
                    acc[i][j] = __builtin_amdgcn_mfma_f32_16x16x32_bf16(
                        af[i], bfr[j], acc[i][j], 0, 0, 0);
        }
        __syncthreads();
    }
}

// 64x64 serial core: 4 waves as 2x2 of 32x32; waves 0-1 stage A, 2-3 stage B.
__device__ __forceinline__ void gemm_core64(const unsigned short* __restrict__ Ab,
                                            const unsigned short* __restrict__ Bb,
                                            int K, int lda, int ldb,
                                            char* ldsA, char* ldsB,
                                            int wave, int lane, int wr, int wc,
                                            int l15, int khi, f32x4 (&acc)[2][2]) {
    for (int k0 = 0; k0 < K; k0 += 64) {
        if (wave < 2)
            stage_gl64(Ab + k0, lda, ldsA, wave, lane);
        else
            stage_gl64(Bb + k0, ldb, ldsB, wave - 2, lane);
        __syncthreads();
#pragma unroll
        for (int kk = 0; kk < 2; ++kk) {
            const int kbyte = kk * 64 + khi;
            bf16x8 af[2], bfr[2];
#pragma unroll
            for (int i = 0; i < 2; ++i)
                af[i] = load_frag(ldsA, wr * 32 + i * 16 + l15, kbyte);
#pragma unroll
            for (int j = 0; j < 2; ++j)
                bfr[j] = load_frag(ldsB, wc * 32 + j * 16 + l15, kbyte);
#pragma unroll
            for (int i = 0; i < 2; ++i)
#pragma unroll
                for (int j = 0; j < 2; ++j)
                    acc[i][j] = __builtin_amdgcn_mfma_f32_16x16x32_bf16(
                        af[i], bfr[j], acc[i][j], 0, 0, 0);
        }
        __syncthreads();
    }
}

enum { BIAS_NONE = 0, BIAS_RANK2 = 2, BIAS_RCOL = 3 };

// 128x128-tile GEMM (high-workgroup dispatches: gemm3).
template <int BIASM, bool OUT_BF16>
__global__ __launch_bounds__(256, 2) void gemm_bf16(
    const unsigned short* __restrict__ A, const unsigned short* __restrict__ B,
    void* __restrict__ C,
    const float* __restrict__ p0, const float* __restrict__ p1,
    const float* __restrict__ p2, const float* __restrict__ p3,
    const unsigned short* __restrict__ rsrc,
    int K, int lda, int ldb, int ldc, long bsA, long bsB, long bsC,
    float scale, int vld1) {
    __shared__ __align__(16) char ldsA[16384];
    __shared__ __align__(16) char ldsB[16384];

    const unsigned gx = gridDim.x, gy = gridDim.y;
    const unsigned lin = blockIdx.x + gx * (blockIdx.y + gy * blockIdx.z);
    const unsigned wg = xcd_swizzle(lin, gx * gy * gridDim.z);
    const int bx = wg % gx;
    const int by = (wg / gx) % gy;
    const int z = wg / (gx * gy);

    const int m0 = by * 128;
    const int n0 = bx * 128;
    const unsigned short* Ab = A + (size_t)z * bsA + (size_t)m0 * lda;
    const unsigned short* Bb = B + (size_t)z * bsB + (size_t)n0 * ldb;

    const int lane = threadIdx.x & 63;
    const int wave = threadIdx.x >> 6;
    const int wm = wave >> 1;
    const int wn = wave & 1;
    const int l15 = lane & 15;
    const int khi = (lane >> 4) << 4;

    f32x4 acc[4][4];
#pragma unroll
    for (int i = 0; i < 4; ++i)
#pragma unroll
        for (int j = 0; j < 4; ++j)
            acc[i][j] = (f32x4){0.f, 0.f, 0.f, 0.f};

    gemm_core(Ab, Bb, K, lda, ldb, ldsA, ldsB, wave, lane, wm, wn, l15, khi, acc);

    const int rbase = (lane >> 4) << 2;
#pragma unroll
    for (int i = 0; i < 4; ++i) {
#pragma unroll
        for (int r = 0; r < 4; ++r) {
            int row = m0 + wm * 64 + i * 16 + rbase + r;
            float rA = 0.f, rB = 0.f;
            if (BIASM == BIAS_RANK2) {
                rA = p0[row];
                rB = p2[z * 768 + row];
            }
#pragma unroll
            for (int j = 0; j < 4; ++j) {
                int col = n0 + wn * 64 + j * 16 + l15;
                float v = acc[i][j][r] * scale;
                if (BIASM == BIAS_RANK2) v += rA * p1[z * vld1 + col] + rB * p3[col];
                if (BIASM == BIAS_RCOL)
                    v += bf2f(rsrc[(size_t)z * 688128 + (size_t)col * 896 + 768]);
                size_t off = (size_t)z * bsC + (size_t)row * ldc + col;
                if (OUT_BF16)
                    ((unsigned short*)C)[off] = f2bf(v);
                else
                    ((float*)C)[off] = v;
            }
        }
    }
}

// 64x64-tile GEMM (low-workgroup mid-chain dispatches).
template <int BIASM, bool OUT_BF16>
__global__ __launch_bounds__(256, 2) void gemm64_bf16(
    const unsigned short* __restrict__ A, const unsigned short* __restrict__ B,
    void* __restrict__ C,
    const float* __restrict__ p0, const float* __restrict__ p1,
    const float* __restrict__ p2, const float* __restrict__ p3,
    const unsigned short* __restrict__ rsrc,
    int K, int lda, int ldb, int ldc, long bsA, long bsB, long bsC,
    float scale, int vld1) {
    __shared__ __align__(16) char ldsA[8192];
    __shared__ __align__(16) char ldsB[8192];

    const unsigned gx = gridDim.x, gy = gridDim.y;
    const unsigned lin = blockIdx.x + gx * (blockIdx.y + gy * blockIdx.z);
    const unsigned wg = xcd_swizzle(lin, gx * gy * gridDim.z);
    const int bx = wg % gx;
    const int by = (wg / gx) % gy;
    const int z = wg / (gx * gy);

    const int m0 = by * 64;
    const int n0 = bx * 64;
    const unsigned short* Ab = A + (size_t)z * bsA + (size_t)m0 * lda;
    const unsigned short* Bb = B + (size_t)z * bsB + (size_t)n0 * ldb;

    const int lane = threadIdx.x & 63;
    const int wave = threadIdx.x >> 6;
    const int wr = wave >> 1;
    const int wc = wave & 1;
    const int l15 = lane & 15;
    const int khi = (lane >> 4) << 4;

    f32x4 acc[2][2];
#pragma unroll
    for (int i = 0; i < 2; ++i)
#pragma unroll
        for (int j = 0; j < 2; ++j)
            acc[i][j] = (f32x4){0.f, 0.f, 0.f, 0.f};

    gemm_core64(Ab, Bb, K, lda, ldb, ldsA, ldsB, wave, lane, wr, wc, l15, khi, acc);

    const int rbase = (lane >> 4) << 2;
#pragma unroll
    for (int i = 0; i < 2; ++i) {
#pragma unroll
        for (int r = 0; r < 4; ++r) {
            int row = m0 + wr * 32 + i * 16 + rbase + r;
            float rA = 0.f, rB = 0.f;
            if (BIASM == BIAS_RANK2) {
                rA = p0[row];
                rB = p2[z * 768 + row];
            }
#pragma unroll
            for (int j = 0; j < 2; ++j) {
                int col = n0 + wc * 32 + j * 16 + l15;
                float v = acc[i][j][r] * scale;
                if (BIASM == BIAS_RANK2) v += rA * p1[z * vld1 + col] + rB * p3[col];
                if (BIASM == BIAS_RCOL)
                    v += bf2f(rsrc[(size_t)z * 688128 + (size_t)col * 896 + 768]);
                size_t off = (size_t)z * bsC + (size_t)row * ldc + col;
                if (OUT_BF16)
                    ((unsigned short*)C)[off] = f2bf(v);
                else
                    ((float*)C)[off] = v;
            }
        }
    }
}

// z=0: Wqt+ rows 0..767 = Wq^T; z=1: Wkt = Wk^T; z=2: Wvb = bf16(Wv);
// z=3: Wqt+ row 768 = bq, rows 769..895 = 0; z=4: zero csum.
__global__ __launch_bounds__(256) void prep_w(const float* __restrict__ Wq,
                                              const float* __restrict__ Wk,
                                              const float* __restrict__ Wv,
                                              const float* __restrict__ bq,
                                              unsigned short* __restrict__ Wqt,
                                              unsigned short* __restrict__ Wkt,
                                              unsigned short* __restrict__ Wvb,
                                              float* __restrict__ csum) {
    const int mode = blockIdx.z;
    const int t = threadIdx.x;
    if (mode == 4) {
        if (blockIdx.x == 0 && blockIdx.y == 0) {
            float4 z4 = {0.f, 0.f, 0.f, 0.f};
            for (int i = t * 4; i < 3072; i += 1024) *(float4*)(csum + i) = z4;
        }
        return;
    }
    if (mode == 3) {
        if (blockIdx.y) return;
        int rr = 768 + (t >> 1);
        int c0 = blockIdx.x * 64 + (t & 1) * 32;
        unsigned short v[32] __attribute__((aligned(16)));
        if (rr == 768) {
#pragma unroll
            for (int j = 0; j < 32; ++j) v[j] = f2bf(bq[c0 + j]);
        } else {
#pragma unroll
            for (int j = 0; j < 32; ++j) v[j] = 0;
        }
        unsigned short* dst = Wqt + (size_t)rr * 768 + c0;
#pragma unroll
        for (int j = 0; j < 4; ++j) *(uint4*)(dst + j * 8) = *(uint4*)&v[j * 8];
        return;
    }
    __shared__ unsigned short tile[64 * 72];
    const float* src = mode == 0 ? Wq : (mode == 1 ? Wk : Wv);
    const int r0 = blockIdx.x * 64;
    const int c0 = blockIdx.y * 64;
    int r = t >> 2, cq = (t & 3) * 16;
    unsigned short v[16] __attribute__((aligned(16)));
    const float* s = src + (size_t)(r0 + r) * 768 + c0 + cq;
#pragma unroll
    for (int j = 0; j < 16; j += 4) {
        float4 f = *(const float4*)(s + j);
        v[j] = f2bf(f.x); v[j + 1] = f2bf(f.y);
        v[j + 2] = f2bf(f.z); v[j + 3] = f2bf(f.w);
    }
    if (mode == 2) {
        unsigned short* dst = Wvb + (size_t)(r0 + r) * 768 + c0 + cq;
        *(uint4*)dst = *(uint4*)&v[0];
        *(uint4*)(dst + 8) = *(uint4*)&v[8];
        return;
    }
    *(uint4*)&tile[r * 72 + cq] = *(uint4*)&v[0];
    *(uint4*)&tile[r * 72 + cq + 8] = *(uint4*)&v[8];
    __syncthreads();
    int dr = t >> 2, sq = (t & 3) * 16;
    unsigned short w[16] __attribute__((aligned(16)));
#pragma unroll
    for (int j = 0; j < 16; ++j) w[j] = tile[(sq + j) * 72 + dr];
    unsigned short* dst = (mode == 0 ? Wqt : Wkt) + (size_t)(c0 + dr) * 768 + r0 + sq;
    *(uint4*)dst = *(uint4*)&w[0];
    *(uint4*)(dst + 8) = *(uint4*)&w[8];
}

// Xbf [4][4096][768], Xt [4][768][4096], csum atomics.
__global__ __launch_bounds__(256) void prep_x(const float* __restrict__ X,
                                              unsigned short* __restrict__ Xbf,
                                              unsigned short* __restrict__ Xt,
                                              float* __restrict__ csum) {
    const int b = blockIdx.z;
    const int s0 = blockIdx.x * 64;
    const int t = threadIdx.x;
    __shared__ unsigned short tile[64 * 72];
    const int d0 = blockIdx.y * 64;
    const float* Xb = X + (size_t)b * 4096 * 768;
    unsigned short* XbfB = Xbf + (size_t)b * 4096 * 768;
    unsigned short* XtB = Xt + (size_t)b * 768 * 4096;
    {
        int r = t >> 2, cq = (t & 3) * 16;
        const float* src = Xb + (size_t)(s0 + r) * 768 + d0 + cq;
        unsigned short v[16] __attribute__((aligned(16)));
#pragma unroll
        for (int j = 0; j < 16; j += 4) {
            float4 f = *(const float4*)(src + j);
            v[j] = f2bf(f.x); v[j + 1] = f2bf(f.y);
            v[j + 2] = f2bf(f.z); v[j + 3] = f2bf(f.w);
        }
        unsigned short* dst = XbfB + (size_t)(s0 + r) * 768 + d0 + cq;
        *(uint4*)dst = *(uint4*)&v[0];
        *(uint4*)(dst + 8) = *(uint4*)&v[8];
        *(uint4*)&tile[r * 72 + cq] = *(uint4*)&v[0];
        *(uint4*)&tile[r * 72 + cq + 8] = *(uint4*)&v[8];
    }
    __syncthreads();
    {
        int dr = t >> 2, sq = (t & 3) * 16;
        unsigned short v[16] __attribute__((aligned(16)));
        float part = 0.f;
#pragma unroll
        for (int j = 0; j < 16; ++j) {
            unsigned short u = tile[(sq + j) * 72 + dr];
            v[j] = u;
            part += bf2f(u);
        }
        unsigned short* dst = XtB + (size_t)(d0 + dr) * 4096 + s0 + sq;
        *(uint4*)dst = *(uint4*)&v[0];
        *(uint4*)(dst + 8) = *(uint4*)&v[8];
        part += __shfl_down(part, 1);
        part += __shfl_down(part, 2);
        if ((t & 3) == 0) atomicAdd(&csum[b * 768 + d0 + dr], part);
    }
}

// Flat grid 3488:
//   wg < 2496: triangular 64x64 Gram partial tile (tile=wg%78, zz=wg/78;
//              b=zz>>3, split=zz&7, K=512) -> packed Gp [zz*78+tile][64][64]
//   wg < 3264: aux u/d2: id=wg-2496, b=id/192, row=(id%192)*4+wave
//   wg >=3264: c2p: row=(wg-3264)*4+wave (<896): c2p[row]=Wqt+[row].bk
__global__ __launch_bounds__(256, 2) void gram2(
    const unsigned short* __restrict__ Xt, unsigned short* __restrict__ Gp,
    const float* __restrict__ Wk, const float* __restrict__ Wv,
    const unsigned short* __restrict__ Wqt,
    const float* __restrict__ bk, const float* __restrict__ bv,
    const float* __restrict__ csum,
    float* __restrict__ u, float* __restrict__ d2, float* __restrict__ c2p) {
    const long PB = 3145728;
    const unsigned wg = xcd_swizzle(blockIdx.x, gridDim.x);
    const int t = threadIdx.x;
    const int lane = t & 63;
    const int wave = t >> 6;

    if (wg >= 3264) {  // c2p
        const int row = (wg - 3264) * 4 + wave;
        float a = 0.f;
        for (int e = lane * 4; e < 768; e += 256) {
            const unsigned short* qr = Wqt + (size_t)row * 768 + e;
            float4 b4 = *(const float4*)(bk + e);
            a += bf2f(qr[0]) * b4.x + bf2f(qr[1]) * b4.y +
                 bf2f(qr[2]) * b4.z + bf2f(qr[3]) * b4.w;
        }
#pragma unroll
        for (int off = 32; off; off >>= 1) a += __shfl_down(a, off);
        if (lane == 0) c2p[row] = a;
        return;
    }
    if (wg >= 2496) {  // u + d2
        const int id = wg - 2496;
        const int b = id / 192;
        const int row = (id % 192) * 4 + wave;
        const float* s = csum + b * 768;
        float aU = 0.f, aD = 0.f;
        for (int e = lane * 4; e < 768; e += 256) {
            float4 wk4 = *(const float4*)(Wk + (size_t)row * 768 + e);
            float4 wv4 = *(const float4*)(Wv + (size_t)row * 768 + e);
            float4 s4 = *(const float4*)(s + e);
            aU += wk4.x * s4.x + wk4.y * s4.y + wk4.z * s4.z + wk4.w * s4.w;
            aD += wv4.x * s4.x + wv4.y * s4.y + wv4.z * s4.z + wv4.w * s4.w;
        }
#pragma unroll
        for (int off = 32; off; off >>= 1) {
            aU += __shfl_down(aU, off);
            aD += __shfl_down(aD, off);
        }
        if (lane == 0) {
            u[b * 768 + row] = aU;
            d2[b * 768 + row] = SCALE * (aD + 4096.f * bv[row]);
        }
        return;
    }

    __shared__ __align__(16) char ldsA[8192];
    __shared__ __align__(16) char ldsB[8192];
    const int wr = wave >> 1;
    const int wc = wave & 1;
    const int l15 = lane & 15;
    const int khi = (lane >> 4) << 4;
    f32x4 acc[2][2];
#pragma unroll
    for (int i = 0; i < 2; ++i)
#pragma unroll
        for (int j = 0; j < 2; ++j)
            acc[i][j] = (f32x4){0.f, 0.f, 0.f, 0.f};
    const int rbase = (lane >> 4) << 2;

    const int tile = wg % 78;
    const int zz = wg / 78;
    const int b = zz >> 3;
    const int koff = (zz & 7) * 512;
    int tt = tile, tby = 0;
    while (tt >= 12 - tby) { tt -= 12 - tby; ++tby; }
    const int m0 = tby * 64;
    const int n0 = (tby + tt) * 64;
    const unsigned short* Ab = Xt + (size_t)b * PB + (size_t)m0 * 4096 + koff;
    const unsigned short* Bb = Xt + (size_t)b * PB + (size_t)n0 * 4096 + koff;
    gemm_core64(Ab, Bb, 512, 4096, 4096, ldsA, ldsB, wave, lane, wr, wc, l15, khi, acc);
    unsigned short* dst = Gp + ((size_t)zz * 78 + tile) * 4096;
#pragma unroll
    for (int i = 0; i < 2; ++i)
#pragma unroll
        for (int r = 0; r < 4; ++r) {
            int rloc = wr * 32 + i * 16 + rbase + r;
#pragma unroll
            for (int j = 0; j < 2; ++j) {
                int cloc = wc * 32 + j * 16 + l15;
                dst[(size_t)rloc * 64 + cloc] = f2bf(acc[i][j][r]);
            }
        }
}

// grid (344,4):
//   x<78: reduce Gp (8 splits) -> 64x64 G tile, mirror off-diag (y=b)
//   78<=x<302: c1p[b][row] = SCALE * Wqt+[row] . u_b   (row=(x-78)*4+wave)
//   x>=302: 64x64 P+ tile, id=(x-302)*4+y in [0,168): 14x12 tiles, K=768
__global__ __launch_bounds__(256, 2) void redvec2(
    const unsigned short* __restrict__ Gp, unsigned short* __restrict__ G,
    const unsigned short* __restrict__ Wqt, const unsigned short* __restrict__ Wkt,
    unsigned short* __restrict__ Pp,
    const float* __restrict__ u, float* __restrict__ c1p) {
    const int b = blockIdx.y;
    const int t = threadIdx.x;
    const int lane = t & 63;
    const int wave = t >> 6;
    if (blockIdx.x >= 302) {  // P+ 64x64, spread over all y
        __shared__ __align__(16) char ldsA[8192];
        __shared__ __align__(16) char ldsB[8192];
        const int id = (blockIdx.x - 302) * 4 + b;
        const int m0 = (id / 12) * 64;
        const int n0 = (id % 12) * 64;
        const int wr = wave >> 1;
        const int wc = wave & 1;
        const int l15 = lane & 15;
        const int khi = (lane >> 4) << 4;
        f32x4 acc[2][2];
#pragma unroll
        for (int i = 0; i < 2; ++i)
#pragma unroll
            for (int j = 0; j < 2; ++j)
                acc[i][j] = (f32x4){0.f, 0.f, 0.f, 0.f};
        gemm_core64(Wqt + (size_t)m0 * 768, Wkt + (size_t)n0 * 768,
                    768, 768, 768, ldsA, ldsB, wave, lane, wr, wc, l15, khi, acc);
        const int rbase = (lane >> 4) << 2;
#pragma unroll
        for (int i = 0; i < 2; ++i)
#pragma unroll
            for (int r = 0; r < 4; ++r) {
                int row = m0 + wr * 32 + i * 16 + rbase + r;
#pragma unroll
                for (int j = 0; j < 2; ++j) {
                    int col = n0 + wc * 32 + j * 16 + l15;
                    Pp[(size_t)row * 768 + col] = f2bf(acc[i][j][r]);
                }
            }
        return;
    }
    if (blockIdx.x >= 78) {  // c1p
        const int row = (blockIdx.x - 78) * 4 + wave;
        const float* ub = u + b * 768;
        float a = 0.f;
        for (int e = lane * 4; e < 768; e += 256) {
            const unsigned short* qr = Wqt + (size_t)row * 768 + e;
            float4 u4 = *(const float4*)(ub + e);
            a += bf2f(qr[0]) * u4.x + bf2f(qr[1]) * u4.y +
                 bf2f(qr[2]) * u4.z + bf2f(qr[3]) * u4.w;
        }
#pragma unroll
        for (int off = 32; off; off >>= 1) a += __shfl_down(a, off);
        if (lane == 0) c1p[b * 896 + row] = SCALE * a;
        return;
    }
    // reduce one 64x64 tile over 8 splits; mirror off-diagonal
    __shared__ unsigned short tl[64 * 72];
    const int tile = blockIdx.x;
    int tt = tile, tby = 0;
    while (tt >= 12 - tby) { tt -= 12 - tby; ++tby; }
    const int tbx = tby + tt;
    const int r = t >> 2;
    const int c0 = (t & 3) * 16;
    float acc[16];
#pragma unroll
    for (int j = 0; j < 16; ++j) acc[j] = 0.f;
    for (int sp = 0; sp < 8; ++sp) {
        const unsigned short* base =
            Gp + ((size_t)(b * 8 + sp) * 78 + tile) * 4096 + (size_t)r * 64 + c0;
#pragma unroll
        for (int j = 0; j < 2; ++j) {
            uint4 qv = *(const uint4*)(base + j * 8);
            const unsigned short* pv = (const unsigned short*)&qv;
#pragma unroll
            for (int k = 0; k < 8; ++k) acc[j * 8 + k] += bf2f(pv[k]);
        }
    }
    unsigned short v[16] __attribute__((aligned(16)));
#pragma unroll
    for (int j = 0; j < 16; ++j) v[j] = f2bf(acc[j]);
    unsigned short* dst = G + (size_t)b * 589824 +
                          (size_t)(tby * 64 + r) * 768 + tbx * 64 + c0;
    *(uint4*)dst = *(uint4*)&v[0];
    *(uint4*)(dst + 8) = *(uint4*)&v[8];
    if (tby != tbx) {
        *(uint4*)&tl[r * 72 + c0] = *(uint4*)&v[0];
        *(uint4*)&tl[r * 72 + c0 + 8] = *(uint4*)&v[8];
        __syncthreads();
        int dr = t >> 2, sq = (t & 3) * 16;
        unsigned short w[16] __attribute__((aligned(16)));
#pragma unroll
        for (int j = 0; j < 16; ++j) w[j] = tl[(sq + j) * 72 + dr];
        unsigned short* dm = G + (size_t)b * 589824 +
                             (size_t)(tbx * 64 + dr) * 768 + tby * 64 + sq;
        *(uint4*)dm = *(uint4*)&w[0];
        *(uint4*)(dm + 8) = *(uint4*)&w[8];
    }
}

extern "C" void kernel_launch(void* const* d_in, const int* in_sizes, int n_in,
                              void* d_out, int out_size, void* d_ws, size_t ws_size,
                              hipStream_t stream) {
    const float* x  = (const float*)d_in[0];
    const float* Wq = (const float*)d_in[1];
    const float* bq = (const float*)d_in[2];
    const float* Wk = (const float*)d_in[3];
    const float* bk = (const float*)d_in[4];
    const float* Wv = (const float*)d_in[5];
    const float* bv = (const float*)d_in[6];
    float* out = (float*)d_out;

    const long PB = 3145728;   // 4096*768
    const long DD = 589824;    // 768*768
    const long DA = 688128;    // 896*768

    unsigned short* ws  = (unsigned short*)d_ws;
    unsigned short* Xbf = ws;                       // 12582912
    unsigned short* Xt  = ws + 12582912;            // 12582912
    unsigned short* Pp  = ws + 25165824;            // 688128
    unsigned short* G   = ws + 25853952;            // 2359296
    unsigned short* Wqt = ws + 28213248;            // 688128 ([896][768])
    unsigned short* Wkt = ws + 28901376;            // 589824
    unsigned short* Wvb = ws + 29491200;            // 589824
    unsigned short* Gp  = ws + 30081024;            // 10223616 used (78*32 64x64)
    unsigned short* C1p = Gp;                       // overlay after redvec2
    unsigned short* At  = Gp + 2752512;             // 2752512
    float* fbase = (float*)(ws + 41091072);
    float* csum = fbase;                            // 3072
    float* u    = fbase + 3072;                     // 3072
    float* c1p  = fbase + 6144;                     // 3584
    float* c2p  = fbase + 9728;                     // 896
    float* d2   = fbase + 10624;                    // 3072

    dim3 blk(256, 1, 1);

    prep_w<<<dim3(12, 12, 5), blk, 0, stream>>>(Wq, Wk, Wv, bq, Wqt, Wkt, Wvb, csum);
    prep_x<<<dim3(64, 12, 4), blk, 0, stream>>>(x, Xbf, Xt, csum);

    // Gram tri 64x64 split-K partials (split=8, K=512) + u/d2 + c2p aux
    gram2<<<dim3(3488, 1, 1), blk, 0, stream>>>(Xt, Gp, Wk, Wv, Wqt, bk, bv,
                                                csum, u, d2, c2p);

    // reduce G (78 tiles) + c1p + P+ (64x64, 168 tiles over 4 y)
    redvec2<<<dim3(344, 4), blk, 0, stream>>>(Gp, G, Wqt, Wkt, Pp, u, c1p);

    // C1+ = P+ ⊠ G   [4][896][768]   (64x64 tiles: 672 wgs)
    gemm64_bf16<BIAS_NONE, true><<<dim3(12, 14, 4), blk, 0, stream>>>(
        Pp, G, C1p, nullptr, nullptr, nullptr, nullptr, nullptr,
        768, 768, 768, 768, 0, DD, DA, 1.0f, 0);

    // At = Wvb ⊠ C1+ (+rank2)   [4][768][896]   (64x64 tiles: 672 wgs)
    gemm64_bf16<BIAS_RANK2, true><<<dim3(14, 12, 4), blk, 0, stream>>>(
        Wvb, C1p, At, bv, c1p, d2, c2p, nullptr,
        768, 768, 768, 896, 0, DA, DA, SCALE, 896);

    // out = Xbf ⊠ At (K=768) + r epilogue (At col 768)  fp32 (128x128: 768 wgs)
    gemm_bf16<BIAS_RCOL, false><<<dim3(6, 32, 4), blk, 0, stream>>>(
        Xbf, At, out, nullptr, nullptr, nullptr, nullptr, At,
        768, 768, 896, 768, PB, DA, PB, 1.0f, 0);
}